// Round 2
// baseline (334.951 us; speedup 1.0000x reference)
//
#include <hip/hip_runtime.h>
#include <hip/hip_cooperative_groups.h>

namespace cg = cooperative_groups;

#define NB 4
#define NC 32
#define NH 32
#define NW 32
#define KK 288                   // 32*3*3 patch length
#define PLANE (NB*NC*NH*NW)      // 131072 elements per plane
#define CHALF 16                 // channels per block (split reduction)
#define NBLK 256                 // cooperative grid: 256 blocks (1/CU, co-resident)
#define NTHR 512                 // 512 threads = 8 waves/block

__device__ __forceinline__ float s3(float v) { return sqrtf(sqrtf(sqrtf(v))); }

// ---------------- phase bodies (shared by fused + fallback kernels) ----------------

// Zero-mean weight rows; padded float4 layout [co][c][r] = {w(r,0),w(r,1),w(r,2),pad}.
__device__ __forceinline__ void prep_phase(int bid, int tid,
        const float* __restrict__ w1, const float* __restrict__ w2,
        float* __restrict__ wf1, float* __restrict__ wf2, float* red)
{
    if (bid >= 2*NC) return;
    const float* src = (bid < NC) ? w1 : w2;
    float* dst = (bid < NC) ? wf1 : wf2;
    const int co = bid & (NC - 1);
    const float a = (tid < KK) ? src[co*KK + tid] : 0.0f;
    red[tid] = a;
    __syncthreads();
    for (int s = NTHR/2; s > 0; s >>= 1) {
        if (tid < s) red[tid] += red[tid + s];
        __syncthreads();
    }
    const float mean = red[0] * (1.0f / (float)KK);
    if (tid < KK) {
        const int c = tid / 9, r9 = tid - c*9, r = r9 / 3, kw = r9 - r*3;
        dst[co*384 + ((c*3 + r) << 2) + kw] = a - mean;
    }
}

// Half-channel norm-dist conv. bid -> (h, chalf, b). Thread (tx,ty): one pixel,
// TWO output channels (ty, ty+16), so each patch ds_read feeds 18 taps and one
// block's staging serves all 32 co.
template<bool STAGE2>
__device__ __forceinline__ void conv_phase(int bid, int tid,
    const float* __restrict__ sy,     // stage1: x plane | stage2: conv1 Y partials [2][PLANE]
    const float* __restrict__ sl,
    const float* __restrict__ su,
    const float* __restrict__ wf,     // prepped weights, float4 [co][c][r]
    float* __restrict__ pY, float* __restrict__ pL, float* __restrict__ pU,
    float4* sP)                        // [c<16][r<3][col<34] float4, 26112 B
{
    const int h     = bid & (NH - 1);
    const int chalf = (bid >> 5) & 1;
    const int b     = bid >> 6;
    const int ch0   = chalf * CHALF;
    const int tx    = tid & 31;
    const int ty    = tid >> 5;       // 0..15

    for (int i = tid; i < CHALF*3*34; i += NTHR) {
        const int c   = i / 102;
        const int rem = i - c*102;
        const int r   = rem / 34;
        const int col = rem - r*34;
        const int gh  = h + r - 1;
        const int gw  = col - 1;
        float vx = 0.0f, vl = 0.0f, vu = 0.0f;
        if ((unsigned)gh < NH && (unsigned)gw < NW) {
            const int g = ((b*NC + ch0 + c)*NH + gh)*NW + gw;
            if (STAGE2) {   // combine conv1 halves + eighth-root (relu no-op: >=0)
                vx = s3(sy[g] + sy[PLANE + g]);
                vl = s3(sl[g] + sl[PLANE + g]);
                vu = s3(su[g] + su[PLANE + g]);
            } else {
                vx = sy[g]; vl = sl[g]; vu = su[g];
            }
        }
        sP[i] = make_float4(vx, vl, vu, 0.0f);
    }
    __syncthreads();

    const int co0 = ty;
    const int co1 = ty + 16;
    const float4* wbA = (const float4*)wf + (co0*NC + ch0)*3;
    const float4* wbB = (const float4*)wf + (co1*NC + ch0)*3;

    float aY0 = 0.0f, aL0 = 0.0f, aU0 = 0.0f;
    float aY1 = 0.0f, aL1 = 0.0f, aU1 = 0.0f;

    auto tap = [&](float wv, float4 p, float& accY, float& accL, float& accU) {
        const float d  = p.x - wv;          // y: |d|^8 = ((d^2)^2)^2
        const float d2 = d*d, d4 = d2*d2;
        accY = fmaf(d4, d4, accY);
        const float a  = p.y - wv;          // dl: max(a, nb, 0)^8
        const float nb = wv - p.z;
        const float m  = fmaxf(fmaxf(a, nb), 0.0f);
        const float m2 = m*m, m4 = m2*m2;
        accL = fmaf(m4, m4, accL);
        const float a2 = a*a, q2 = nb*nb;   // du: max(a^2, nb^2)^4
        const float mm2 = fmaxf(a2, q2);
        const float mm4 = mm2*mm2;
        accU = fmaf(mm4, mm4, accU);
    };

    // Software-pipelined weight fetch: load c+1's 6 float4 while computing c.
    float4 cA0 = wbA[0], cA1 = wbA[1], cA2 = wbA[2];
    float4 cB0 = wbB[0], cB1 = wbB[1], cB2 = wbB[2];

    for (int c = 0; c < CHALF; ++c) {
        const int cn = (c < CHALF-1) ? c + 1 : c;
        const float4 nA0 = wbA[cn*3+0], nA1 = wbA[cn*3+1], nA2 = wbA[cn*3+2];
        const float4 nB0 = wbB[cn*3+0], nB1 = wbB[cn*3+1], nB2 = wbB[cn*3+2];

        const int pb = c*102 + tx;
        const float4 p00 = sP[pb +  0], p01 = sP[pb +  1], p02 = sP[pb +  2];
        const float4 p10 = sP[pb + 34], p11 = sP[pb + 35], p12 = sP[pb + 36];
        const float4 p20 = sP[pb + 68], p21 = sP[pb + 69], p22 = sP[pb + 70];

        tap(cA0.x, p00, aY0, aL0, aU0); tap(cA0.y, p01, aY0, aL0, aU0); tap(cA0.z, p02, aY0, aL0, aU0);
        tap(cB0.x, p00, aY1, aL1, aU1); tap(cB0.y, p01, aY1, aL1, aU1); tap(cB0.z, p02, aY1, aL1, aU1);
        tap(cA1.x, p10, aY0, aL0, aU0); tap(cA1.y, p11, aY0, aL0, aU0); tap(cA1.z, p12, aY0, aL0, aU0);
        tap(cB1.x, p10, aY1, aL1, aU1); tap(cB1.y, p11, aY1, aL1, aU1); tap(cB1.z, p12, aY1, aL1, aU1);
        tap(cA2.x, p20, aY0, aL0, aU0); tap(cA2.y, p21, aY0, aL0, aU0); tap(cA2.z, p22, aY0, aL0, aU0);
        tap(cB2.x, p20, aY1, aL1, aU1); tap(cB2.y, p21, aY1, aL1, aU1); tap(cB2.z, p22, aY1, aL1, aU1);

        cA0 = nA0; cA1 = nA1; cA2 = nA2;
        cB0 = nB0; cB1 = nB1; cB2 = nB2;
    }

    const int o0 = ((b*NC + co0)*NH + h)*NW + tx;
    const int o1 = o0 + 16*NH*NW;
    pY[chalf*PLANE + o0] = aY0;
    pL[chalf*PLANE + o0] = aL0;
    pU[chalf*PLANE + o0] = aU0;
    pY[chalf*PLANE + o1] = aY1;
    pL[chalf*PLANE + o1] = aL1;
    pU[chalf*PLANE + o1] = aU1;
}

// Combine conv2 halves, eighth-root, add residual, relu. One element per thread.
__device__ __forceinline__ void epilogue_phase(int o,
    const float* __restrict__ pY, const float* __restrict__ pL, const float* __restrict__ pU,
    const float* __restrict__ x,  const float* __restrict__ l,  const float* __restrict__ u,
    float* __restrict__ out)
{
    const float y  = s3(pY[o] + pY[PLANE + o]);
    const float dl = s3(pL[o] + pL[PLANE + o]);
    const float du = s3(pU[o] + pU[PLANE + o]);
    out[o]           = fmaxf(y  + x[o], 0.0f);
    out[PLANE + o]   = fmaxf(dl + l[o], 0.0f);
    out[2*PLANE + o] = fmaxf(du + u[o], 0.0f);
}

// ---------------- fused cooperative megakernel ----------------

__global__ __launch_bounds__(NTHR, 1) void fused_k(
    const float* __restrict__ x, const float* __restrict__ l, const float* __restrict__ u,
    const float* __restrict__ w1, const float* __restrict__ w2,
    float* __restrict__ wf1, float* __restrict__ wf2,
    float* __restrict__ p1Y, float* __restrict__ p1L, float* __restrict__ p1U,
    float* __restrict__ p2Y, float* __restrict__ p2L, float* __restrict__ p2U,
    float* __restrict__ out)
{
    __shared__ float4 sP[CHALF*3*34];
    __shared__ float red[NTHR];
    cg::grid_group grid = cg::this_grid();
    const int bid = blockIdx.x;
    const int tid = threadIdx.x;

    prep_phase(bid, tid, w1, w2, wf1, wf2, red);
    __threadfence();
    grid.sync();

    conv_phase<false>(bid, tid, x, l, u, wf1, p1Y, p1L, p1U, sP);
    __threadfence();
    grid.sync();

    conv_phase<true>(bid, tid, p1Y, p1L, p1U, wf2, p2Y, p2L, p2U, sP);
    __threadfence();
    grid.sync();

    epilogue_phase(bid*NTHR + tid, p2Y, p2L, p2U, x, l, u, out);
}

// ---------------- fallback split kernels (if cooperative launch unavailable) ----------------

__global__ __launch_bounds__(NTHR) void prep_only_k(
        const float* __restrict__ w1, const float* __restrict__ w2,
        float* __restrict__ wf1, float* __restrict__ wf2)
{
    __shared__ float red[NTHR];
    prep_phase(blockIdx.x, threadIdx.x, w1, w2, wf1, wf2, red);
}

template<bool STAGE2>
__global__ __launch_bounds__(NTHR) void conv_only_k(
    const float* __restrict__ sy, const float* __restrict__ sl, const float* __restrict__ su,
    const float* __restrict__ wf,
    float* __restrict__ pY, float* __restrict__ pL, float* __restrict__ pU)
{
    __shared__ float4 sP[CHALF*3*34];
    conv_phase<STAGE2>(blockIdx.x, threadIdx.x, sy, sl, su, wf, pY, pL, pU, sP);
}

__global__ __launch_bounds__(NTHR) void epilogue_only_k(
    const float* __restrict__ pY, const float* __restrict__ pL, const float* __restrict__ pU,
    const float* __restrict__ x,  const float* __restrict__ l,  const float* __restrict__ u,
    float* __restrict__ out)
{
    epilogue_phase(blockIdx.x*NTHR + threadIdx.x, pY, pL, pU, x, l, u, out);
}

// ---------------- launcher ----------------

extern "C" void kernel_launch(void* const* d_in, const int* in_sizes, int n_in,
                              void* d_out, int out_size, void* d_ws, size_t ws_size,
                              hipStream_t stream)
{
    const float* x  = (const float*)d_in[0];
    const float* l  = (const float*)d_in[1];
    const float* u  = (const float*)d_in[2];
    const float* w1 = (const float*)d_in[3];
    const float* w2 = (const float*)d_in[4];
    float* ws  = (float*)d_ws;
    float* wf1 = ws;                        // 12288 floats (padded float4 layout)
    float* wf2 = wf1 + 12288;
    float* p1Y = wf2 + 12288;               // conv1 partials: [2][PLANE] each
    float* p1L = p1Y + 2*PLANE;
    float* p1U = p1L + 2*PLANE;
    float* p2Y = p1U + 2*PLANE;             // conv2 partials
    float* p2L = p2Y + 2*PLANE;
    float* p2U = p2L + 2*PLANE;
    float* out = (float*)d_out;

    void* args[] = { (void*)&x, (void*)&l, (void*)&u, (void*)&w1, (void*)&w2,
                     (void*)&wf1, (void*)&wf2,
                     (void*)&p1Y, (void*)&p1L, (void*)&p1U,
                     (void*)&p2Y, (void*)&p2L, (void*)&p2U, (void*)&out };

    hipError_t err = hipLaunchCooperativeKernel((const void*)fused_k,
                                                dim3(NBLK), dim3(NTHR), args, 0, stream);
    if (err != hipSuccess) {
        (void)hipGetLastError();            // clear error, use split path
        prep_only_k<<<2*NC, NTHR, 0, stream>>>(w1, w2, wf1, wf2);
        conv_only_k<false><<<NBLK, NTHR, 0, stream>>>(x, l, u, wf1, p1Y, p1L, p1U);
        conv_only_k<true ><<<NBLK, NTHR, 0, stream>>>(p1Y, p1L, p1U, wf2, p2Y, p2L, p2U);
        epilogue_only_k<<<NBLK, NTHR, 0, stream>>>(p2Y, p2L, p2U, x, l, u, out);
    }
}

// Round 3
// 112.055 us; speedup vs baseline: 2.9892x; 2.9892x over previous
//
#include <hip/hip_runtime.h>

#define NB 4
#define NC 32
#define NH 32
#define NW 32
#define KK 288                   // 32*3*3 patch length
#define PLANE (NB*NC*NH*NW)      // 131072 elements per plane

__device__ __forceinline__ float s3(float v) { return sqrtf(sqrtf(sqrtf(v))); }

// Zero-mean weight rows; write padded float4 layout [co][c][r] = {w(r,0),w(r,1),w(r,2),pad}.
__global__ __launch_bounds__(256) void prep_weights_k(
        const float* __restrict__ w1, const float* __restrict__ w2,
        float* __restrict__ wf1, float* __restrict__ wf2)
{
    const int row = blockIdx.x;                   // 0..63
    const float* src = (row < NC) ? w1 : w2;
    float* dst = (row < NC) ? wf1 : wf2;
    const int co = row & (NC - 1);
    const int tid = threadIdx.x;
    __shared__ float red[256];
    const float a = src[co*KK + tid];                              // tid < 256 < 288
    const float b = (tid + 256 < KK) ? src[co*KK + tid + 256] : 0.0f;
    red[tid] = a + b;
    __syncthreads();
    for (int s = 128; s > 0; s >>= 1) {
        if (tid < s) red[tid] += red[tid + s];
        __syncthreads();
    }
    const float mean = red[0] * (1.0f / (float)KK);
    // element e -> float offset co*384 + (c*3+r)*4 + kw, where e = c*9 + r*3 + kw
    {
        const int e = tid, c = e / 9, r9 = e - c*9, r = r9 / 3, kw = r9 - r*3;
        dst[co*384 + ((c*3 + r) << 2) + kw] = a - mean;
    }
    if (tid + 256 < KK) {
        const int e = tid + 256, c = e / 9, r9 = e - c*9, r = r9 / 3, kw = r9 - r*3;
        dst[co*384 + ((c*3 + r) << 2) + kw] = b - mean;
    }
}

// Full-channel norm-dist conv: block stages ALL 32 input channels (52 KB LDS) and
// computes 16 output channels -> no split reduction, no partials.
// Block = 32(w) x 8(ty); thread = one pixel, TWO co (co0=cog*16+ty, co1=co0+8),
// so each patch ds_read feeds 18 taps (LDS pipe stays under the VALU floor).
// Grid = (h=32, cog=2, b=4) -> 256 blocks.
// STAGE1: reads x/l/u, writes s3(acc) bound planes (relu no-op: >=0).
// STAGE2: reads stage1 planes, fuses residual + relu epilogue, writes out.
template<bool STAGE2>
__global__ __launch_bounds__(256, 1) void conv_full_k(
    const float* __restrict__ sy, const float* __restrict__ sl, const float* __restrict__ su,
    const float* __restrict__ wf,                                    // prepped float4 weights
    const float* __restrict__ rx, const float* __restrict__ rl, const float* __restrict__ ru,
    float* __restrict__ oY, float* __restrict__ oL, float* __restrict__ oU)
{
    const int h   = blockIdx.x;
    const int cog = blockIdx.y;
    const int b   = blockIdx.z;
    const int tx  = threadIdx.x;
    const int ty  = threadIdx.y;
    const int tid = ty * 32 + tx;

    // Patch halo, xlu-interleaved: [c<32][r<3][col<34] float4 (w unused). 52224 B.
    __shared__ float4 sP[NC*3*34];

    for (int i = tid; i < NC*3*34; i += 256) {
        const int c   = i / 102;
        const int rem = i - c*102;
        const int r   = rem / 34;
        const int col = rem - r*34;
        const int gh  = h + r - 1;
        const int gw  = col - 1;
        float vx = 0.0f, vl = 0.0f, vu = 0.0f;
        if ((unsigned)gh < NH && (unsigned)gw < NW) {
            const int g = ((b*NC + c)*NH + gh)*NW + gw;
            vx = sy[g]; vl = sl[g]; vu = su[g];
        }
        sP[i] = make_float4(vx, vl, vu, 0.0f);
    }
    __syncthreads();

    const int co0 = cog*16 + ty;
    const int co1 = co0 + 8;
    const float4* wbA = (const float4*)wf + co0*NC*3;
    const float4* wbB = (const float4*)wf + co1*NC*3;

    float aY0 = 0.0f, aL0 = 0.0f, aU0 = 0.0f;
    float aY1 = 0.0f, aL1 = 0.0f, aU1 = 0.0f;

    auto tap = [&](float wv, float4 p, float& accY, float& accL, float& accU) {
        const float d  = p.x - wv;          // y: |d|^8 = ((d^2)^2)^2
        const float d2 = d*d, d4 = d2*d2;
        accY = fmaf(d4, d4, accY);
        const float a  = p.y - wv;          // dl: max(a, nb, 0)^8
        const float nb = wv - p.z;
        const float m  = fmaxf(fmaxf(a, nb), 0.0f);
        const float m2 = m*m, m4 = m2*m2;
        accL = fmaf(m4, m4, accL);
        const float a2 = a*a, q2 = nb*nb;   // du: max(a^2, nb^2)^4
        const float mm2 = fmaxf(a2, q2);
        const float mm4 = mm2*mm2;
        accU = fmaf(mm4, mm4, accU);
    };

    // Software-pipelined weight fetch: load c+1's 6 float4 while computing c.
    float4 cA0 = wbA[0], cA1 = wbA[1], cA2 = wbA[2];
    float4 cB0 = wbB[0], cB1 = wbB[1], cB2 = wbB[2];

    for (int c = 0; c < NC; ++c) {
        const int cn = (c < NC-1) ? c + 1 : c;
        const float4 nA0 = wbA[cn*3+0], nA1 = wbA[cn*3+1], nA2 = wbA[cn*3+2];
        const float4 nB0 = wbB[cn*3+0], nB1 = wbB[cn*3+1], nB2 = wbB[cn*3+2];

        const int pb = c*102 + tx;
        const float4 p00 = sP[pb +  0], p01 = sP[pb +  1], p02 = sP[pb +  2];
        const float4 p10 = sP[pb + 34], p11 = sP[pb + 35], p12 = sP[pb + 36];
        const float4 p20 = sP[pb + 68], p21 = sP[pb + 69], p22 = sP[pb + 70];

        tap(cA0.x, p00, aY0, aL0, aU0); tap(cA0.y, p01, aY0, aL0, aU0); tap(cA0.z, p02, aY0, aL0, aU0);
        tap(cB0.x, p00, aY1, aL1, aU1); tap(cB0.y, p01, aY1, aL1, aU1); tap(cB0.z, p02, aY1, aL1, aU1);
        tap(cA1.x, p10, aY0, aL0, aU0); tap(cA1.y, p11, aY0, aL0, aU0); tap(cA1.z, p12, aY0, aL0, aU0);
        tap(cB1.x, p10, aY1, aL1, aU1); tap(cB1.y, p11, aY1, aL1, aU1); tap(cB1.z, p12, aY1, aL1, aU1);
        tap(cA2.x, p20, aY0, aL0, aU0); tap(cA2.y, p21, aY0, aL0, aU0); tap(cA2.z, p22, aY0, aL0, aU0);
        tap(cB2.x, p20, aY1, aL1, aU1); tap(cB2.y, p21, aY1, aL1, aU1); tap(cB2.z, p22, aY1, aL1, aU1);

        cA0 = nA0; cA1 = nA1; cA2 = nA2;
        cB0 = nB0; cB1 = nB1; cB2 = nB2;
    }

    const int o0 = ((b*NC + co0)*NH + h)*NW + tx;
    const int o1 = o0 + 8*NH*NW;

    if (STAGE2) {   // fused epilogue: eighth-root + residual + relu
        oY[o0]         = fmaxf(s3(aY0) + rx[o0], 0.0f);
        oY[o1]         = fmaxf(s3(aY1) + rx[o1], 0.0f);
        oL[o0]         = fmaxf(s3(aL0) + rl[o0], 0.0f);
        oL[o1]         = fmaxf(s3(aL1) + rl[o1], 0.0f);
        oU[o0]         = fmaxf(s3(aU0) + ru[o0], 0.0f);
        oU[o1]         = fmaxf(s3(aU1) + ru[o1], 0.0f);
    } else {        // eighth-root; relu no-op (s3 >= 0)
        oY[o0] = s3(aY0); oY[o1] = s3(aY1);
        oL[o0] = s3(aL0); oL[o1] = s3(aL1);
        oU[o0] = s3(aU0); oU[o1] = s3(aU1);
    }
}

extern "C" void kernel_launch(void* const* d_in, const int* in_sizes, int n_in,
                              void* d_out, int out_size, void* d_ws, size_t ws_size,
                              hipStream_t stream)
{
    const float* x  = (const float*)d_in[0];
    const float* l  = (const float*)d_in[1];
    const float* u  = (const float*)d_in[2];
    const float* w1 = (const float*)d_in[3];
    const float* w2 = (const float*)d_in[4];
    float* ws  = (float*)d_ws;
    float* wf1 = ws;                        // 12288 floats (padded float4 layout)
    float* wf2 = wf1 + 12288;
    float* y1  = wf2 + 12288;               // conv1 output planes (final bounds)
    float* l1  = y1 + PLANE;
    float* u1  = l1 + PLANE;
    float* out = (float*)d_out;

    prep_weights_k<<<64, 256, 0, stream>>>(w1, w2, wf1, wf2);

    dim3 blk(32, 8);
    dim3 grd(NH, 2, NB);                    // h, cog, b -> 256 blocks
    conv_full_k<false><<<grd, blk, 0, stream>>>(x, l, u, wf1,
                                                nullptr, nullptr, nullptr,
                                                y1, l1, u1);
    conv_full_k<true ><<<grd, blk, 0, stream>>>(y1, l1, u1, wf2,
                                                x, l, u,
                                                out, out + PLANE, out + 2*PLANE);
}

// Round 4
// 103.038 us; speedup vs baseline: 3.2508x; 1.0875x over previous
//
#include <hip/hip_runtime.h>

#define NB 4
#define NC 32
#define NH 32
#define NW 32
#define KK 288                   // 32*3*3 patch length
#define PLANE (NB*NC*NH*NW)      // 131072 elements per plane
#define CHALF 16                 // channels per block (split reduction)

typedef float v2f __attribute__((ext_vector_type(2)));

__device__ __forceinline__ float s3(float v) { return sqrtf(sqrtf(sqrtf(v))); }
__device__ __forceinline__ v2f pkfma(v2f a, v2f b, v2f c) { return __builtin_elementwise_fma(a, b, c); }
__device__ __forceinline__ v2f pkmax(v2f a, v2f b) { return __builtin_elementwise_max(a, b); }

// Zero-mean weight rows; PAIR-INTERLEAVED packed layout for v_pk_* math:
// pair q = cog*8 + (co&7) covers (co0 = cog*16 + t, co1 = co0 + 8); slot = A/B.
// Per (q,c,r): 8 floats {A.k0,B.k0, A.k1,B.k1, A.k2,B.k2, pad,pad}.
// float offset = ((q*NC + c)*3 + r)*8 + kw*2 + slot.
__global__ __launch_bounds__(256) void prep_weights_k(
        const float* __restrict__ w1, const float* __restrict__ w2,
        float* __restrict__ wf1, float* __restrict__ wf2)
{
    const int row = blockIdx.x;                   // 0..63
    const float* src = (row < NC) ? w1 : w2;
    float* dst = (row < NC) ? wf1 : wf2;
    const int co = row & (NC - 1);
    const int tid = threadIdx.x;
    __shared__ float red[256];
    const float a = src[co*KK + tid];                              // tid < 256 < 288
    const float b = (tid + 256 < KK) ? src[co*KK + tid + 256] : 0.0f;
    red[tid] = a + b;
    __syncthreads();
    for (int s = 128; s > 0; s >>= 1) {
        if (tid < s) red[tid] += red[tid + s];
        __syncthreads();
    }
    const float mean = red[0] * (1.0f / (float)KK);
    const int q    = ((co >> 4) << 3) | (co & 7);
    const int slot = (co >> 3) & 1;
    {
        const int e = tid, c = e / 9, r9 = e - c*9, r = r9 / 3, kw = r9 - r*3;
        dst[((q*NC + c)*3 + r)*8 + kw*2 + slot] = a - mean;
    }
    if (tid + 256 < KK) {
        const int e = tid + 256, c = e / 9, r9 = e - c*9, r = r9 / 3, kw = r9 - r*3;
        dst[((q*NC + c)*3 + r)*8 + kw*2 + slot] = b - mean;
    }
}

// Half-channel norm-dist conv, PACKED over the two output channels per thread.
// Block = 32(w) x 8(ty); thread = one pixel, co pair (cog*16+ty, +8).
// Grid = (h=32, cog*2+chalf=4, b=4) -> 512 blocks, 2 blocks/CU, 2 waves/SIMD.
// STAGE1: stages x/l/u. STAGE2: stages s3(p0+p1) from conv1 partials.
// Both write partial (pre-root) sums to pY/pL/pU at [chalf*PLANE + o].
template<bool STAGE2>
__global__ __launch_bounds__(256, 2) void normdist_conv_k(
    const float* __restrict__ sy,     // stage1: x plane | stage2: conv1 Y partials [2][PLANE]
    const float* __restrict__ sl,
    const float* __restrict__ su,
    const float* __restrict__ wf,     // prepped pair-interleaved weights
    float* __restrict__ pY, float* __restrict__ pL, float* __restrict__ pU)
{
    const int h     = blockIdx.x;
    const int cog   = blockIdx.y >> 1;
    const int chalf = blockIdx.y & 1;
    const int ch0   = chalf * CHALF;
    const int b     = blockIdx.z;
    const int tx    = threadIdx.x;
    const int ty    = threadIdx.y;
    const int tid   = ty * 32 + tx;

    // Patch halo, xlu-interleaved: [c<16][r<3][col<34] float4 (w unused). 26112 B.
    __shared__ float4 sP[CHALF*3*34];

    for (int i = tid; i < CHALF*3*34; i += 256) {
        const int c   = i / 102;
        const int rem = i - c*102;
        const int r   = rem / 34;
        const int col = rem - r*34;
        const int gh  = h + r - 1;
        const int gw  = col - 1;
        float vx = 0.0f, vl = 0.0f, vu = 0.0f;
        if ((unsigned)gh < NH && (unsigned)gw < NW) {
            const int g = ((b*NC + ch0 + c)*NH + gh)*NW + gw;
            if (STAGE2) {   // combine conv1 halves + eighth-root (relu no-op: >=0)
                vx = s3(sy[g] + sy[PLANE + g]);
                vl = s3(sl[g] + sl[PLANE + g]);
                vu = s3(su[g] + su[PLANE + g]);
            } else {
                vx = sy[g]; vl = sl[g]; vu = su[g];
            }
        }
        sP[i] = make_float4(vx, vl, vu, 0.0f);
    }
    __syncthreads();

    // Weight base for this thread's co pair: q = cog*8 + ty, starting at channel ch0.
    const int q = cog*8 + ty;
    const float4* wq = (const float4*)wf + (q*NC + ch0)*3*2;   // 6 float4 per channel

    v2f aY = {0.0f, 0.0f}, aL = {0.0f, 0.0f}, aU = {0.0f, 0.0f};

    // Packed tap: w = {wA, wB} for the co pair; p broadcast.
    auto tap2 = [&](v2f w, const float4& p) {
        const v2f px = {p.x, p.x};
        const v2f py = {p.y, p.y};
        const v2f pz = {p.z, p.z};
        const v2f d  = px - w;              // y: |d|^8 = ((d^2)^2)^2
        const v2f d2 = d*d, d4 = d2*d2;
        aY = pkfma(d4, d4, aY);
        const v2f a  = py - w;              // dl: max(a, nb, 0)^8
        const v2f nb = w - pz;
        const v2f z  = {0.0f, 0.0f};
        const v2f m  = pkmax(pkmax(a, nb), z);
        const v2f m2 = m*m, m4 = m2*m2;
        aL = pkfma(m4, m4, aL);
        const v2f a2 = a*a, q2 = nb*nb;     // du: max(a^2, nb^2)^4
        const v2f mm2 = pkmax(a2, q2);
        const v2f mm4 = mm2*mm2;
        aU = pkfma(mm4, mm4, aU);
    };

    // Software-pipelined weight fetch: load c+1's 6 float4 while computing c.
    float4 c0 = wq[0], c1 = wq[1], c2 = wq[2], c3 = wq[3], c4 = wq[4], c5 = wq[5];

    for (int c = 0; c < CHALF; ++c) {
        const int cn = (c < CHALF-1) ? c + 1 : c;
        const float4 n0 = wq[cn*6+0], n1 = wq[cn*6+1], n2 = wq[cn*6+2];
        const float4 n3 = wq[cn*6+3], n4 = wq[cn*6+4], n5 = wq[cn*6+5];

        const int pb = c*102 + tx;
        const float4 p00 = sP[pb +  0], p01 = sP[pb +  1], p02 = sP[pb +  2];
        const float4 p10 = sP[pb + 34], p11 = sP[pb + 35], p12 = sP[pb + 36];
        const float4 p20 = sP[pb + 68], p21 = sP[pb + 69], p22 = sP[pb + 70];

        tap2((v2f){c0.x, c0.y}, p00); tap2((v2f){c0.z, c0.w}, p01); tap2((v2f){c1.x, c1.y}, p02);
        tap2((v2f){c2.x, c2.y}, p10); tap2((v2f){c2.z, c2.w}, p11); tap2((v2f){c3.x, c3.y}, p12);
        tap2((v2f){c4.x, c4.y}, p20); tap2((v2f){c4.z, c4.w}, p21); tap2((v2f){c5.x, c5.y}, p22);

        c0 = n0; c1 = n1; c2 = n2; c3 = n3; c4 = n4; c5 = n5;
    }

    const int co0 = cog*16 + ty;
    const int o0 = ((b*NC + co0)*NH + h)*NW + tx;
    const int o1 = o0 + 8*NH*NW;
    pY[chalf*PLANE + o0] = aY.x;
    pL[chalf*PLANE + o0] = aL.x;
    pU[chalf*PLANE + o0] = aU.x;
    pY[chalf*PLANE + o1] = aY.y;
    pL[chalf*PLANE + o1] = aL.y;
    pU[chalf*PLANE + o1] = aU.y;
}

// Combine conv2 halves, eighth-root, add residual, relu, write out. float4-vectorized.
__global__ __launch_bounds__(256) void epilogue_k(
    const float* __restrict__ pY, const float* __restrict__ pL, const float* __restrict__ pU,
    const float* __restrict__ x,  const float* __restrict__ l,  const float* __restrict__ u,
    float* __restrict__ out)
{
    const int i = blockIdx.x*256 + threadIdx.x;     // float4 index, PLANE/4 total
    const float4* pY4 = (const float4*)pY;
    const float4* pL4 = (const float4*)pL;
    const float4* pU4 = (const float4*)pU;
    const float4* x4  = (const float4*)x;
    const float4* l4  = (const float4*)l;
    const float4* u4  = (const float4*)u;
    float4* out4 = (float4*)out;
    const int Q = PLANE/4;

    const float4 ya = pY4[i], yb = pY4[Q + i];
    const float4 la = pL4[i], lb = pL4[Q + i];
    const float4 ua = pU4[i], ub = pU4[Q + i];
    const float4 xr = x4[i], lr = l4[i], ur = u4[i];

    float4 oy, ol, ou;
    oy.x = fmaxf(s3(ya.x + yb.x) + xr.x, 0.0f);
    oy.y = fmaxf(s3(ya.y + yb.y) + xr.y, 0.0f);
    oy.z = fmaxf(s3(ya.z + yb.z) + xr.z, 0.0f);
    oy.w = fmaxf(s3(ya.w + yb.w) + xr.w, 0.0f);
    ol.x = fmaxf(s3(la.x + lb.x) + lr.x, 0.0f);
    ol.y = fmaxf(s3(la.y + lb.y) + lr.y, 0.0f);
    ol.z = fmaxf(s3(la.z + lb.z) + lr.z, 0.0f);
    ol.w = fmaxf(s3(la.w + lb.w) + lr.w, 0.0f);
    ou.x = fmaxf(s3(ua.x + ub.x) + ur.x, 0.0f);
    ou.y = fmaxf(s3(ua.y + ub.y) + ur.y, 0.0f);
    ou.z = fmaxf(s3(ua.z + ub.z) + ur.z, 0.0f);
    ou.w = fmaxf(s3(ua.w + ub.w) + ur.w, 0.0f);

    out4[i]       = oy;
    out4[Q + i]   = ol;
    out4[2*Q + i] = ou;
}

extern "C" void kernel_launch(void* const* d_in, const int* in_sizes, int n_in,
                              void* d_out, int out_size, void* d_ws, size_t ws_size,
                              hipStream_t stream)
{
    const float* x  = (const float*)d_in[0];
    const float* l  = (const float*)d_in[1];
    const float* u  = (const float*)d_in[2];
    const float* w1 = (const float*)d_in[3];
    const float* w2 = (const float*)d_in[4];
    float* ws  = (float*)d_ws;
    float* wf1 = ws;                        // 12288 floats (pair-interleaved layout)
    float* wf2 = wf1 + 12288;
    float* p1Y = wf2 + 12288;               // conv1 partials: [2][PLANE] each
    float* p1L = p1Y + 2*PLANE;
    float* p1U = p1L + 2*PLANE;
    float* p2Y = p1U + 2*PLANE;             // conv2 partials
    float* p2L = p2Y + 2*PLANE;
    float* p2U = p2L + 2*PLANE;
    float* out = (float*)d_out;

    prep_weights_k<<<64, 256, 0, stream>>>(w1, w2, wf1, wf2);

    dim3 blk(32, 8);
    dim3 grd(NH, 4, NB);                    // h, cog*2+chalf, b  -> 512 blocks
    normdist_conv_k<false><<<grd, blk, 0, stream>>>(x, l, u, wf1, p1Y, p1L, p1U);
    normdist_conv_k<true ><<<grd, blk, 0, stream>>>(p1Y, p1L, p1U, wf2, p2Y, p2L, p2U);
    epilogue_k<<<PLANE/1024, 256, 0, stream>>>(p2Y, p2L, p2U, x, l, u, out);
}